// Round 13
// baseline (198.585 us; speedup 1.0000x reference)
//
#include <hip/hip_runtime.h>

#define N_ROWS 65536
#define DIM    512
#define BM     64
#define THREADS 512
#define XB_SZ   65536
#define BBUF_SZ 32768

typedef unsigned short ushort_t;
typedef __bf16 bf16x8 __attribute__((ext_vector_type(8)));
typedef float  f32x4  __attribute__((ext_vector_type(4)));

union BU { uint4 u; bf16x8 b; };

__device__ __forceinline__ unsigned f2bf(float f) {
    unsigned u = __float_as_uint(f);
    return (u + 0x7fffu + ((u >> 16) & 1u)) >> 16;   // RNE f32->bf16
}

// Branchless tanh-form GELU: max abs err ~3e-3 vs exact erf GELU.
__device__ __forceinline__ float gelu_fast(float x) {
    float x2 = x * x;
    float u  = x * (0.7978845608f + 0.0356774081f * x2);
    float a  = fabsf(u);
    float t  = __expf(-2.f * a);
    float th = 1.f - 2.f * t * __builtin_amdgcn_rcpf(1.f + t);
    th = copysignf(th, u);
    return 0.5f * x * (1.f + th);
}

// async global->LDS, 16 bytes per lane; lds dest = wave-uniform base + lane*16
__device__ __forceinline__ void gload_lds16(const ushort_t* g, char* l) {
    __builtin_amdgcn_global_load_lds(
        (const __attribute__((address_space(1))) unsigned int*)g,
        (__attribute__((address_space(3))) unsigned int*)l, 16, 0, 0);
}

// K1a: transpose + gamma-scale (W1 only) + bf16.  W (f32 [k][n]) -> WT (bf16 [n][k])
__global__ void prep_weights(const float* __restrict__ W1,
                             const float* __restrict__ W2,
                             const float* __restrict__ gamma,
                             ushort_t* __restrict__ WT) {
    __shared__ float tile[32][33];
    const int z = blockIdx.z;
    const float* W = z ? W2 : W1;
    ushort_t* dst = WT + (size_t)z * DIM * DIM;
    int n0 = blockIdx.x * 32;
    int k0 = blockIdx.y * 32;
    for (int i = threadIdx.y; i < 32; i += 8) {
        float g = z ? 1.f : gamma[k0 + i];
        tile[i][threadIdx.x] = W[(size_t)(k0 + i) * DIM + n0 + threadIdx.x] * g;
    }
    __syncthreads();
    for (int i = threadIdx.y; i < 32; i += 8)
        dst[(size_t)(n0 + i) * DIM + k0 + threadIdx.x] =
            (ushort_t)f2bf(tile[threadIdx.x][i]);
}

// K1b: s1[c] = sum_k gamma[k]*W1[k][c];  bb1[c] = b1[c] + sum_k beta[k]*W1[k][c]
__global__ void prep_vecs(const float* __restrict__ W1,
                          const float* __restrict__ gamma,
                          const float* __restrict__ beta,
                          const float* __restrict__ b1,
                          float* __restrict__ s1, float* __restrict__ bb1) {
    const int c = blockIdx.x * 256 + threadIdx.x;
    float s = 0.f, tt = 0.f;
    #pragma unroll 8
    for (int k = 0; k < DIM; ++k) {
        float w = W1[(size_t)k * DIM + c];
        s  += gamma[k] * w;
        tt += beta[k]  * w;
    }
    s1[c]  = s;
    bb1[c] = b1[c] + tt;
}

// Fused: stage bf16(x)+stats -> GEMM1(LN-folded,+GELU) -> GEMM2(+bias,+residual)
// 8 waves, BM=64, per-wave 64x64 tile (acc[4][4]=64 AGPR): halves A LDS-read
// traffic, doubles MFMA per ds_read. LDS 129KB -> 1 block/CU anyway, so
// launch_bounds(512,2) gives a 256-reg budget: no spill possible.
// K-loop: barrier-free wave-private B DMA double-buffer (R11 pattern, vmcnt(4)).
__global__ __launch_bounds__(THREADS, 2) void fused_mlp(
    const float* __restrict__ x, const ushort_t* __restrict__ W1T,
    const float* __restrict__ s1, const float* __restrict__ bb1,
    const ushort_t* __restrict__ W2T, const float* __restrict__ b2,
    float* __restrict__ out)
{
    __shared__ __align__(16) char smem[XB_SZ + 2 * BBUF_SZ];  // 128 KB: xb | Bbuf0 | Bbuf1
    __shared__ float2 strow[BM];                              // {rstd, -rstd*mu}
    const int t    = threadIdx.x;
    const int wave = t >> 6;             // 0..7
    const int lane = t & 63;
    const int l15  = lane & 15;
    const int kb   = lane >> 4;          // 0..3
    const size_t rowbase = (size_t)blockIdx.x * BM;

    // ---- staging: wave stages 4 chunks of 16 n-rows each (64 cols total) ---
    const int nl = lane >> 2;            // 0..15 (n within 16-row chunk)
    const int sl = lane & 3;             // 16B slot within 64B row
    const int ssw = sl ^ ((nl >> 1) & 3);               // source-chunk permutation
    const unsigned stage_goff = (unsigned)((wave * 64 + nl) * DIM + ssw * 8); // elements
    char* const bwin0 = smem + XB_SZ + wave * 4096;     // + buf*BBUF_SZ

    // stage W1T slice 0 (4 DMAs) — overlaps all of P1
    #pragma unroll
    for (int j = 0; j < 4; ++j)
        gload_lds16(W1T + stage_goff + j * 16 * DIM, bwin0 + j * 1024);

    // Per-col folded-LN vectors (4 col-frags per wave)
    float s1v[4], bbv[4];
    #pragma unroll
    for (int n = 0; n < 4; ++n) {
        int c = wave * 64 + n * 16 + l15;
        s1v[n] = s1[c];
        bbv[n] = bb1[c];
    }

    // ---------------- Phase 1: stream x -> bf16 LDS (swizzled) + row stats ---
    {
        const int r   = t >> 3;          // 0..63
        const int sub = t & 7;           // 8 threads/row, 64 cols each
        const float4* xr = (const float4*)(x + (rowbase + r) * DIM) + sub * 16;
        const unsigned swz  = (unsigned)((r & 7) << 4);
        const unsigned base = (unsigned)(r * 1024 + sub * 128);
        float s = 0.f, ss = 0.f;
        #pragma unroll
        for (int q = 0; q < 8; ++q) {
            float4 a = xr[2 * q], b = xr[2 * q + 1];
            s  += a.x + a.y + a.z + a.w + b.x + b.y + b.z + b.w;
            ss += a.x*a.x + a.y*a.y + a.z*a.z + a.w*a.w
                + b.x*b.x + b.y*b.y + b.z*b.z + b.w*b.w;
            uint4 p;
            p.x = f2bf(a.x) | (f2bf(a.y) << 16);
            p.y = f2bf(a.z) | (f2bf(a.w) << 16);
            p.z = f2bf(b.x) | (f2bf(b.y) << 16);
            p.w = f2bf(b.z) | (f2bf(b.w) << 16);
            *(uint4*)(smem + ((base + (unsigned)(q * 16)) ^ swz)) = p;
        }
        #pragma unroll
        for (int m = 1; m < 8; m <<= 1) {
            s  += __shfl_xor(s,  m);
            ss += __shfl_xor(ss, m);
        }
        const float mean = s * (1.f / 512.f);
        const float var  = ss * (1.f / 512.f) - mean * mean;
        const float rstd = rsqrtf(var + 1e-5f);
        if (sub == 0) strow[r] = make_float2(rstd, -rstd * mean);
    }
    __syncthreads();   // xb + strow visible; slice-0 DMA drained by barrier

    // ---- fragment addressing ----
    const unsigned amask = (unsigned)((l15 & 7) << 4);
    unsigned abase[4];
    #pragma unroll
    for (int m = 0; m < 4; ++m)
        abase[m] = (unsigned)((m * 16 + l15) * 1024 + kb * 16);
    unsigned boff[4];   // B frag read offsets within a Bbuf (swizzled slot)
    #pragma unroll
    for (int n = 0; n < 4; ++n)
        boff[n] = (unsigned)((wave * 64 + n * 16 + l15) * 64 +
                             ((kb ^ ((l15 >> 1) & 3)) * 16));

    f32x4 acc[4][4];

    // ---------------- Phase 2: GEMM1 (LN folded) + GELU -> LDS --------------
    {
        #pragma unroll
        for (int m = 0; m < 4; ++m)
            #pragma unroll
            for (int n = 0; n < 4; ++n)
                acc[m][n] = f32x4{0.f, 0.f, 0.f, 0.f};

        #pragma unroll 2
        for (int ks = 0; ks < 16; ++ks) {
            const int cur = ks & 1;
            asm volatile("s_waitcnt lgkmcnt(0)" ::: "memory");
            if (ks < 15) {               // stage next k-slice into other buffer
                const ushort_t* s0 = W1T + stage_goff + (ks + 1) * 32;
                char* l0 = bwin0 + (cur ^ 1) * BBUF_SZ;
                #pragma unroll
                for (int j = 0; j < 4; ++j)
                    gload_lds16(s0 + j * 16 * DIM, l0 + j * 1024);
                asm volatile("s_waitcnt vmcnt(4)" ::: "memory");  // slice ks landed
            } else {
                asm volatile("s_waitcnt vmcnt(0)" ::: "memory");
            }
            __builtin_amdgcn_sched_barrier(0);
            const char* bb = smem + XB_SZ + cur * BBUF_SZ;
            bf16x8 a[4], b[4];
            #pragma unroll
            for (int n = 0; n < 4; ++n) {
                BU u; u.u = *(const uint4*)(bb + boff[n]);
                b[n] = u.b;
            }
            #pragma unroll
            for (int m = 0; m < 4; ++m) {
                BU u; u.u = *(const uint4*)(smem + ((abase[m] + (unsigned)(ks * 64)) ^ amask));
                a[m] = u.b;
            }
            #pragma unroll
            for (int m = 0; m < 4; ++m)
                #pragma unroll
                for (int n = 0; n < 4; ++n)
                    acc[m][n] = __builtin_amdgcn_mfma_f32_16x16x32_bf16(
                        a[m], b[n], acc[m][n], 0, 0, 0);
        }
        __syncthreads();   // all waves done reading xb

        // stage W2T slice 0 — overlaps GELU epilogue
        #pragma unroll
        for (int j = 0; j < 4; ++j)
            gload_lds16(W2T + stage_goff + j * 16 * DIM, bwin0 + j * 1024);

        // epilogue: LN scalars + GELU -> overwrite xb with h1 (bf16, swizzled)
        #pragma unroll
        for (int m = 0; m < 4; ++m) {
            #pragma unroll
            for (int i = 0; i < 4; ++i) {
                const int r = m * 16 + kb * 4 + i;
                const float2 sv = strow[r];
                #pragma unroll
                for (int n = 0; n < 4; ++n) {
                    const int c = wave * 64 + n * 16 + l15;
                    float v = sv.x * acc[m][n][i] + sv.y * s1v[n] + bbv[n];
                    float g = gelu_fast(v);
                    *(ushort_t*)(smem + (unsigned)((r * 1024 + c * 2) ^ ((r & 7) << 4)))
                        = (ushort_t)f2bf(g);
                }
            }
        }
    }
    __syncthreads();   // h1 visible; W2T slice-0 DMA drained by barrier

    // ---------------- Phase 3: GEMM2 + bias2 + residual -> out (f32) --------
    {
        #pragma unroll
        for (int m = 0; m < 4; ++m)
            #pragma unroll
            for (int n = 0; n < 4; ++n)
                acc[m][n] = f32x4{0.f, 0.f, 0.f, 0.f};

        #pragma unroll 2
        for (int ks = 0; ks < 16; ++ks) {
            const int cur = ks & 1;
            asm volatile("s_waitcnt lgkmcnt(0)" ::: "memory");
            if (ks < 15) {
                const ushort_t* s0 = W2T + stage_goff + (ks + 1) * 32;
                char* l0 = bwin0 + (cur ^ 1) * BBUF_SZ;
                #pragma unroll
                for (int j = 0; j < 4; ++j)
                    gload_lds16(s0 + j * 16 * DIM, l0 + j * 1024);
                asm volatile("s_waitcnt vmcnt(4)" ::: "memory");
            } else {
                asm volatile("s_waitcnt vmcnt(0)" ::: "memory");
            }
            __builtin_amdgcn_sched_barrier(0);
            const char* bb = smem + XB_SZ + cur * BBUF_SZ;
            bf16x8 a[4], b[4];
            #pragma unroll
            for (int n = 0; n < 4; ++n) {
                BU u; u.u = *(const uint4*)(bb + boff[n]);
                b[n] = u.b;
            }
            #pragma unroll
            for (int m = 0; m < 4; ++m) {
                BU u; u.u = *(const uint4*)(smem + ((abase[m] + (unsigned)(ks * 64)) ^ amask));
                a[m] = u.b;
            }
            #pragma unroll
            for (int m = 0; m < 4; ++m)
                #pragma unroll
                for (int n = 0; n < 4; ++n)
                    acc[m][n] = __builtin_amdgcn_mfma_f32_16x16x32_bf16(
                        a[m], b[n], acc[m][n], 0, 0, 0);
        }
        #pragma unroll
        for (int n = 0; n < 4; ++n) {
            const int c = wave * 64 + n * 16 + l15;
            const float bias = b2[c];
            #pragma unroll
            for (int m = 0; m < 4; ++m) {
                #pragma unroll
                for (int i = 0; i < 4; ++i) {
                    const int r = m * 16 + kb * 4 + i;
                    const size_t gi = (rowbase + (size_t)r) * DIM + (size_t)c;
                    out[gi] = x[gi] + (acc[m][n][i] + bias);
                }
            }
        }
    }
}

extern "C" void kernel_launch(void* const* d_in, const int* in_sizes, int n_in,
                              void* d_out, int out_size, void* d_ws, size_t ws_size,
                              hipStream_t stream) {
    const float* x     = (const float*)d_in[0];
    const float* gamma = (const float*)d_in[1];
    const float* beta  = (const float*)d_in[2];
    const float* W1    = (const float*)d_in[3];
    const float* b1    = (const float*)d_in[4];
    const float* W2    = (const float*)d_in[5];
    const float* b2    = (const float*)d_in[6];
    float* out = (float*)d_out;

    char* ws = (char*)d_ws;
    ushort_t* WT  = (ushort_t*)ws;                       // 1 MB: W1gT | W2T
    float*    s1  = (float*)(ws + 1048576);              // 2 KB
    float*    bb1 = (float*)(ws + 1048576 + 2048);       // 2 KB

    prep_weights<<<dim3(DIM / 32, DIM / 32, 2), dim3(32, 8), 0, stream>>>(W1, W2, gamma, WT);
    prep_vecs<<<dim3(2), dim3(256), 0, stream>>>(W1, gamma, beta, b1, s1, bb1);
    fused_mlp<<<dim3(N_ROWS / BM), dim3(THREADS), 0, stream>>>(
        x, WT, s1, bb1, WT + DIM * DIM, b2, out);
}

// Round 14
// 193.312 us; speedup vs baseline: 1.0273x; 1.0273x over previous
//
#include <hip/hip_runtime.h>

#define N_ROWS 65536
#define DIM    512
#define BM     64
#define THREADS 1024
#define XB_SZ   65536
#define BBUF_SZ 32768

typedef unsigned short ushort_t;
typedef __bf16 bf16x8 __attribute__((ext_vector_type(8)));
typedef float  f32x4  __attribute__((ext_vector_type(4)));

union BU { uint4 u; bf16x8 b; };

__device__ __forceinline__ unsigned f2bf(float f) {
    unsigned u = __float_as_uint(f);
    return (u + 0x7fffu + ((u >> 16) & 1u)) >> 16;   // RNE f32->bf16
}

// Branchless tanh-form GELU: max abs err ~3e-3 vs exact erf GELU.
__device__ __forceinline__ float gelu_fast(float x) {
    float x2 = x * x;
    float u  = x * (0.7978845608f + 0.0356774081f * x2);
    float a  = fabsf(u);
    float t  = __expf(-2.f * a);
    float th = 1.f - 2.f * t * __builtin_amdgcn_rcpf(1.f + t);
    th = copysignf(th, u);
    return 0.5f * x * (1.f + th);
}

// async global->LDS, 16 bytes per lane; lds dest = wave-uniform base + lane*16
__device__ __forceinline__ void gload_lds16(const ushort_t* g, char* l) {
    __builtin_amdgcn_global_load_lds(
        (const __attribute__((address_space(1))) unsigned int*)g,
        (__attribute__((address_space(3))) unsigned int*)l, 16, 0, 0);
}

// K1a: transpose + gamma-scale (W1 only) + bf16.  W (f32 [k][n]) -> WT (bf16 [n][k])
__global__ void prep_weights(const float* __restrict__ W1,
                             const float* __restrict__ W2,
                             const float* __restrict__ gamma,
                             ushort_t* __restrict__ WT) {
    __shared__ float tile[32][33];
    const int z = blockIdx.z;
    const float* W = z ? W2 : W1;
    ushort_t* dst = WT + (size_t)z * DIM * DIM;
    int n0 = blockIdx.x * 32;
    int k0 = blockIdx.y * 32;
    for (int i = threadIdx.y; i < 32; i += 8) {
        float g = z ? 1.f : gamma[k0 + i];
        tile[i][threadIdx.x] = W[(size_t)(k0 + i) * DIM + n0 + threadIdx.x] * g;
    }
    __syncthreads();
    for (int i = threadIdx.y; i < 32; i += 8)
        dst[(size_t)(n0 + i) * DIM + k0 + threadIdx.x] =
            (ushort_t)f2bf(tile[threadIdx.x][i]);
}

// K1b: s1[c] = sum_k gamma[k]*W1[k][c];  bb1[c] = b1[c] + sum_k beta[k]*W1[k][c]
__global__ void prep_vecs(const float* __restrict__ W1,
                          const float* __restrict__ gamma,
                          const float* __restrict__ beta,
                          const float* __restrict__ b1,
                          float* __restrict__ s1, float* __restrict__ bb1) {
    const int c = blockIdx.x * 256 + threadIdx.x;
    float s = 0.f, tt = 0.f;
    #pragma unroll 8
    for (int k = 0; k < DIM; ++k) {
        float w = W1[(size_t)k * DIM + c];
        s  += gamma[k] * w;
        tt += beta[k]  * w;
    }
    s1[c]  = s;
    bb1[c] = b1[c] + tt;
}

// Fused: stage bf16(x)+stats -> GEMM1(LN-folded,+GELU) -> GEMM2(+bias,+residual)
// R11 frame (best: 195.6us) + P1 LDS-write conflict fix: per-lane chunk
// rotation p=(q+(sub>>1))&3 maps the quarter-wave's 16 writes onto all 8
// distinct 16B slots (was 2 slots -> ~8-way conflict).
__global__ __launch_bounds__(THREADS, 4) void fused_mlp(
    const float* __restrict__ x, const ushort_t* __restrict__ W1T,
    const float* __restrict__ s1, const float* __restrict__ bb1,
    const ushort_t* __restrict__ W2T, const float* __restrict__ b2,
    float* __restrict__ out)
{
    __shared__ __align__(16) char smem[XB_SZ + 2 * BBUF_SZ];  // 128 KB: xb | Bbuf0 | Bbuf1
    __shared__ float2 strow[BM];                              // {rstd, -rstd*mu}
    const int t    = threadIdx.x;
    const int wave = t >> 6;             // 0..15
    const int lane = t & 63;
    const int l15  = lane & 15;
    const int kb   = lane >> 4;          // 0..3
    const size_t rowbase = (size_t)blockIdx.x * BM;

    // ---- staging constants: wave stages 2 windows of 16 n-rows each --------
    const int nl = lane >> 2;            // 0..15 (n within window)
    const int sl = lane & 3;             // 16B slot within 64B row
    const int ssw = sl ^ ((nl >> 1) & 3);               // source-chunk permutation
    const unsigned stage_goff = (unsigned)((wave * 32 + nl) * DIM + ssw * 8); // elements
    char* const bwin0 = smem + XB_SZ + wave * 2048;     // + buf*BBUF_SZ; +1024 -> window 1

    // earliest possible: stage W1T k-step 0 into buf0 (overlaps all of P1)
    gload_lds16(W1T + stage_goff, bwin0);
    gload_lds16(W1T + stage_goff + 16 * DIM, bwin0 + 1024);

    // Per-col folded-LN vectors
    float s1v[2], bbv[2];
    #pragma unroll
    for (int n = 0; n < 2; ++n) {
        int c = wave * 32 + n * 16 + l15;
        s1v[n] = s1[c];
        bbv[n] = bb1[c];
    }

    // ---------------- Phase 1: stream x -> bf16 LDS (swizzled) + row stats ---
    {
        const int r   = t >> 4;          // 0..63
        const int sub = t & 15;          // 16 threads/row, 32 cols each
        const float4* xr = (const float4*)(x + (rowbase + r) * DIM) + sub * 8;
        const unsigned swz  = (unsigned)((r & 7) << 4);
        const unsigned base = (unsigned)(r * 1024 + sub * 64);
        const int rot = (sub >> 1) & 3;  // per-lane chunk rotation (conflict fix)
        float s = 0.f, ss = 0.f;
        #pragma unroll
        for (int q = 0; q < 4; ++q) {
            const int p = (q + rot) & 3;
            float4 a = xr[2 * p], b = xr[2 * p + 1];
            s  += a.x + a.y + a.z + a.w + b.x + b.y + b.z + b.w;
            ss += a.x*a.x + a.y*a.y + a.z*a.z + a.w*a.w
                + b.x*b.x + b.y*b.y + b.z*b.z + b.w*b.w;
            uint4 pk;
            pk.x = f2bf(a.x) | (f2bf(a.y) << 16);
            pk.y = f2bf(a.z) | (f2bf(a.w) << 16);
            pk.z = f2bf(b.x) | (f2bf(b.y) << 16);
            pk.w = f2bf(b.z) | (f2bf(b.w) << 16);
            *(uint4*)(smem + ((base + (unsigned)(p * 16)) ^ swz)) = pk;
        }
        #pragma unroll
        for (int m = 1; m < 16; m <<= 1) {
            s  += __shfl_xor(s,  m);
            ss += __shfl_xor(ss, m);
        }
        const float mean = s * (1.f / 512.f);
        const float var  = ss * (1.f / 512.f) - mean * mean;
        const float rstd = rsqrtf(var + 1e-5f);
        if (sub == 0) strow[r] = make_float2(rstd, -rstd * mean);
    }
    __syncthreads();   // xb + strow visible; buf0 DMA drained by barrier

    // ---- fragment addressing ----
    const unsigned amask = (unsigned)((l15 & 7) << 4);
    unsigned abase[4];
    #pragma unroll
    for (int m = 0; m < 4; ++m)
        abase[m] = (unsigned)((m * 16 + l15) * 1024 + kb * 16);
    unsigned boff[2];   // B frag read offsets within a Bbuf (swizzled slot)
    #pragma unroll
    for (int n = 0; n < 2; ++n)
        boff[n] = (unsigned)((wave * 32 + n * 16 + l15) * 64 +
                             ((kb ^ ((l15 >> 1) & 3)) * 16));

    f32x4 acc[4][2];

    // ---------------- Phase 2: GEMM1 (LN folded) + GELU -> LDS --------------
    {
        #pragma unroll
        for (int m = 0; m < 4; ++m)
            #pragma unroll
            for (int n = 0; n < 2; ++n)
                acc[m][n] = f32x4{0.f, 0.f, 0.f, 0.f};

        #pragma unroll 2
        for (int ks = 0; ks < 16; ++ks) {
            const int cur = ks & 1;
            // prev step's ds_reads complete so the DMA below can't overwrite
            // a buffer still being sampled.
            asm volatile("s_waitcnt lgkmcnt(0)" ::: "memory");
            if (ks < 15) {               // stage next k-slice into other buffer
                const ushort_t* s0 = W1T + stage_goff + (ks + 1) * 32;
                char* l0 = bwin0 + (cur ^ 1) * BBUF_SZ;
                gload_lds16(s0, l0);
                gload_lds16(s0 + 16 * DIM, l0 + 1024);
                asm volatile("s_waitcnt vmcnt(2)" ::: "memory");  // slice ks landed
            } else {
                asm volatile("s_waitcnt vmcnt(0)" ::: "memory");
            }
            __builtin_amdgcn_sched_barrier(0);
            const char* bb = smem + XB_SZ + cur * BBUF_SZ;
            bf16x8 a[4], b[2];
            #pragma unroll
            for (int n = 0; n < 2; ++n) {
                BU u; u.u = *(const uint4*)(bb + boff[n]);
                b[n] = u.b;
            }
            #pragma unroll
            for (int m = 0; m < 4; ++m) {
                BU u; u.u = *(const uint4*)(smem + ((abase[m] + (unsigned)(ks * 64)) ^ amask));
                a[m] = u.b;
            }
            #pragma unroll
            for (int m = 0; m < 4; ++m)
                #pragma unroll
                for (int n = 0; n < 2; ++n)
                    acc[m][n] = __builtin_amdgcn_mfma_f32_16x16x32_bf16(
                        a[m], b[n], acc[m][n], 0, 0, 0);
        }
        __syncthreads();   // all waves done reading xb

        // stage W2T k-step 0 into buf0 — overlaps GELU epilogue
        gload_lds16(W2T + stage_goff, bwin0);
        gload_lds16(W2T + stage_goff + 16 * DIM, bwin0 + 1024);

        // epilogue: LN scalars + GELU -> overwrite xb with h1 (bf16, swizzled)
        #pragma unroll
        for (int m = 0; m < 4; ++m) {
            #pragma unroll
            for (int i = 0; i < 4; ++i) {
                const int r = m * 16 + kb * 4 + i;
                const float2 sv = strow[r];
                #pragma unroll
                for (int n = 0; n < 2; ++n) {
                    const int c = wave * 32 + n * 16 + l15;
                    float v = sv.x * acc[m][n][i] + sv.y * s1v[n] + bbv[n];
                    float g = gelu_fast(v);
                    *(ushort_t*)(smem + (unsigned)((r * 1024 + c * 2) ^ ((r & 7) << 4)))
                        = (ushort_t)f2bf(g);
                }
            }
        }
    }
    __syncthreads();   // h1 visible; W2T slice0 DMA drained by barrier

    // ---------------- Phase 3: GEMM2 + bias2 + residual -> out (f32) --------
    {
        #pragma unroll
        for (int m = 0; m < 4; ++m)
            #pragma unroll
            for (int n = 0; n < 2; ++n)
                acc[m][n] = f32x4{0.f, 0.f, 0.f, 0.f};

        #pragma unroll 2
        for (int ks = 0; ks < 16; ++ks) {
            const int cur = ks & 1;
            asm volatile("s_waitcnt lgkmcnt(0)" ::: "memory");
            if (ks < 15) {
                const ushort_t* s0 = W2T + stage_goff + (ks + 1) * 32;
                char* l0 = bwin0 + (cur ^ 1) * BBUF_SZ;
                gload_lds16(s0, l0);
                gload_lds16(s0 + 16 * DIM, l0 + 1024);
                asm volatile("s_waitcnt vmcnt(2)" ::: "memory");
            } else {
                asm volatile("s_waitcnt vmcnt(0)" ::: "memory");
            }
            __builtin_amdgcn_sched_barrier(0);
            const char* bb = smem + XB_SZ + cur * BBUF_SZ;
            bf16x8 a[4], b[2];
            #pragma unroll
            for (int n = 0; n < 2; ++n) {
                BU u; u.u = *(const uint4*)(bb + boff[n]);
                b[n] = u.b;
            }
            #pragma unroll
            for (int m = 0; m < 4; ++m) {
                BU u; u.u = *(const uint4*)(smem + ((abase[m] + (unsigned)(ks * 64)) ^ amask));
                a[m] = u.b;
            }
            #pragma unroll
            for (int m = 0; m < 4; ++m)
                #pragma unroll
                for (int n = 0; n < 2; ++n)
                    acc[m][n] = __builtin_amdgcn_mfma_f32_16x16x32_bf16(
                        a[m], b[n], acc[m][n], 0, 0, 0);
        }
        #pragma unroll
        for (int n = 0; n < 2; ++n) {
            const int c = wave * 32 + n * 16 + l15;
            const float bias = b2[c];
            #pragma unroll
            for (int m = 0; m < 4; ++m) {
                #pragma unroll
                for (int i = 0; i < 4; ++i) {
                    const int r = m * 16 + kb * 4 + i;
                    const size_t gi = (rowbase + (size_t)r) * DIM + (size_t)c;
                    out[gi] = x[gi] + (acc[m][n][i] + bias);
                }
            }
        }
    }
}

extern "C" void kernel_launch(void* const* d_in, const int* in_sizes, int n_in,
                              void* d_out, int out_size, void* d_ws, size_t ws_size,
                              hipStream_t stream) {
    const float* x     = (const float*)d_in[0];
    const float* gamma = (const float*)d_in[1];
    const float* beta  = (const float*)d_in[2];
    const float* W1    = (const float*)d_in[3];
    const float* b1    = (const float*)d_in[4];
    const float* W2    = (const float*)d_in[5];
    const float* b2    = (const float*)d_in[6];
    float* out = (float*)d_out;

    char* ws = (char*)d_ws;
    ushort_t* WT  = (ushort_t*)ws;                       // 1 MB: W1gT | W2T
    float*    s1  = (float*)(ws + 1048576);              // 2 KB
    float*    bb1 = (float*)(ws + 1048576 + 2048);       // 2 KB

    prep_weights<<<dim3(DIM / 32, DIM / 32, 2), dim3(32, 8), 0, stream>>>(W1, W2, gamma, WT);
    prep_vecs<<<dim3(2), dim3(256), 0, stream>>>(W1, gamma, beta, b1, s1, bb1);
    fused_mlp<<<dim3(N_ROWS / BM), dim3(THREADS), 0, stream>>>(
        x, WT, s1, bb1, WT + DIM * DIM, b2, out);
}

// Round 15
// 173.032 us; speedup vs baseline: 1.1477x; 1.1172x over previous
//
#include <hip/hip_runtime.h>
#include <hip/hip_bf16.h>

#define N_ROWS 65536
#define DIM    512
#define BM     64
#define THREADS 1024
#define XB_SZ   65536
#define BBUF_SZ 32768

typedef unsigned short ushort_t;
typedef __bf16 bf16x8 __attribute__((ext_vector_type(8)));
typedef float  f32x4  __attribute__((ext_vector_type(4)));

union BU { uint4 u; bf16x8 b; };
union BFU { __hip_bfloat162 h2; unsigned u; };

// Packed f32x2 -> bf16x2 (RNE) — compiler emits v_cvt_pk_bf16_f32.
__device__ __forceinline__ unsigned pk_bf16(float lo, float hi) {
    BFU z; z.h2 = __float22bfloat162_rn(float2{lo, hi});
    return z.u;
}

__device__ __forceinline__ unsigned f2bf(float f) {
    unsigned u = __float_as_uint(f);
    return (u + 0x7fffu + ((u >> 16) & 1u)) >> 16;   // RNE f32->bf16 (prep only)
}

// Branchless tanh-form GELU: max abs err ~3e-3 vs exact erf GELU.
__device__ __forceinline__ float gelu_fast(float x) {
    float x2 = x * x;
    float u  = x * (0.7978845608f + 0.0356774081f * x2);
    float a  = fabsf(u);
    float t  = __expf(-2.f * a);
    float th = 1.f - 2.f * t * __builtin_amdgcn_rcpf(1.f + t);
    th = copysignf(th, u);
    return 0.5f * x * (1.f + th);
}

// async global->LDS, 16 bytes per lane; lds dest = wave-uniform base + lane*16
__device__ __forceinline__ void gload_lds16(const ushort_t* g, char* l) {
    __builtin_amdgcn_global_load_lds(
        (const __attribute__((address_space(1))) unsigned int*)g,
        (__attribute__((address_space(3))) unsigned int*)l, 16, 0, 0);
}

// K1a: transpose + gamma-scale (W1 only) + bf16.  W (f32 [k][n]) -> WT (bf16 [n][k])
__global__ void prep_weights(const float* __restrict__ W1,
                             const float* __restrict__ W2,
                             const float* __restrict__ gamma,
                             ushort_t* __restrict__ WT) {
    __shared__ float tile[32][33];
    const int z = blockIdx.z;
    const float* W = z ? W2 : W1;
    ushort_t* dst = WT + (size_t)z * DIM * DIM;
    int n0 = blockIdx.x * 32;
    int k0 = blockIdx.y * 32;
    for (int i = threadIdx.y; i < 32; i += 8) {
        float g = z ? 1.f : gamma[k0 + i];
        tile[i][threadIdx.x] = W[(size_t)(k0 + i) * DIM + n0 + threadIdx.x] * g;
    }
    __syncthreads();
    for (int i = threadIdx.y; i < 32; i += 8)
        dst[(size_t)(n0 + i) * DIM + k0 + threadIdx.x] =
            (ushort_t)f2bf(tile[threadIdx.x][i]);
}

// K1b (parallel): s1[c] = sum_k gamma[k]*W1[k][c];  bb1[c] = b1[c] + sum_k beta[k]*W1[k][c]
// 16 blocks x 256 thr; block b covers cols b*32..b*32+31; 8-way k-split + LDS reduce.
__global__ void prep_vecs(const float* __restrict__ W1,
                          const float* __restrict__ gamma,
                          const float* __restrict__ beta,
                          const float* __restrict__ b1,
                          float* __restrict__ s1, float* __restrict__ bb1) {
    __shared__ float red_s[8][32], red_t[8][32];
    const int cl = threadIdx.x & 31;
    const int kp = threadIdx.x >> 5;          // 0..7
    const int c  = blockIdx.x * 32 + cl;
    float s = 0.f, tt = 0.f;
    #pragma unroll 4
    for (int k = kp * 64; k < kp * 64 + 64; ++k) {
        float w = W1[(size_t)k * DIM + c];
        s  += gamma[k] * w;
        tt += beta[k]  * w;
    }
    red_s[kp][cl] = s; red_t[kp][cl] = tt;
    __syncthreads();
    if (kp == 0) {
        float as = 0.f, at = 0.f;
        #pragma unroll
        for (int j = 0; j < 8; ++j) { as += red_s[j][cl]; at += red_t[j][cl]; }
        s1[c]  = as;
        bb1[c] = b1[c] + at;
    }
}

// Fused: stage bf16(x)+stats -> GEMM1(LN-folded,+GELU) -> GEMM2(+bias,+residual)
// R14 frame (best: 193.3us) + native cvt_pk bf16 packing + setprio around MFMA.
__global__ __launch_bounds__(THREADS, 4) void fused_mlp(
    const float* __restrict__ x, const ushort_t* __restrict__ W1T,
    const float* __restrict__ s1, const float* __restrict__ bb1,
    const ushort_t* __restrict__ W2T, const float* __restrict__ b2,
    float* __restrict__ out)
{
    __shared__ __align__(16) char smem[XB_SZ + 2 * BBUF_SZ];  // 128 KB: xb | Bbuf0 | Bbuf1
    __shared__ float2 strow[BM];                              // {rstd, -rstd*mu}
    const int t    = threadIdx.x;
    const int wave = t >> 6;             // 0..15
    const int lane = t & 63;
    const int l15  = lane & 15;
    const int kb   = lane >> 4;          // 0..3
    const size_t rowbase = (size_t)blockIdx.x * BM;

    // ---- staging constants: wave stages 2 windows of 16 n-rows each --------
    const int nl = lane >> 2;            // 0..15 (n within window)
    const int sl = lane & 3;             // 16B slot within 64B row
    const int ssw = sl ^ ((nl >> 1) & 3);               // source-chunk permutation
    const unsigned stage_goff = (unsigned)((wave * 32 + nl) * DIM + ssw * 8); // elements
    char* const bwin0 = smem + XB_SZ + wave * 2048;     // + buf*BBUF_SZ; +1024 -> window 1

    // earliest possible: stage W1T k-step 0 into buf0 (overlaps all of P1)
    gload_lds16(W1T + stage_goff, bwin0);
    gload_lds16(W1T + stage_goff + 16 * DIM, bwin0 + 1024);

    // Per-col folded-LN vectors
    float s1v[2], bbv[2];
    #pragma unroll
    for (int n = 0; n < 2; ++n) {
        int c = wave * 32 + n * 16 + l15;
        s1v[n] = s1[c];
        bbv[n] = bb1[c];
    }

    // ---------------- Phase 1: stream x -> bf16 LDS (swizzled) + row stats ---
    {
        const int r   = t >> 4;          // 0..63
        const int sub = t & 15;          // 16 threads/row, 32 cols each
        const float4* xr = (const float4*)(x + (rowbase + r) * DIM) + sub * 8;
        const unsigned swz  = (unsigned)((r & 7) << 4);
        const unsigned base = (unsigned)(r * 1024 + sub * 64);
        const int rot = (sub >> 1) & 3;  // per-lane chunk rotation
        float s = 0.f, ss = 0.f;
        #pragma unroll
        for (int q = 0; q < 4; ++q) {
            const int p = (q + rot) & 3;
            float4 a = xr[2 * p], b = xr[2 * p + 1];
            s  += a.x + a.y + a.z + a.w + b.x + b.y + b.z + b.w;
            ss += a.x*a.x + a.y*a.y + a.z*a.z + a.w*a.w
                + b.x*b.x + b.y*b.y + b.z*b.z + b.w*b.w;
            uint4 pk;
            pk.x = pk_bf16(a.x, a.y);
            pk.y = pk_bf16(a.z, a.w);
            pk.z = pk_bf16(b.x, b.y);
            pk.w = pk_bf16(b.z, b.w);
            *(uint4*)(smem + ((base + (unsigned)(p * 16)) ^ swz)) = pk;
        }
        #pragma unroll
        for (int m = 1; m < 16; m <<= 1) {
            s  += __shfl_xor(s,  m);
            ss += __shfl_xor(ss, m);
        }
        const float mean = s * (1.f / 512.f);
        const float var  = ss * (1.f / 512.f) - mean * mean;
        const float rstd = rsqrtf(var + 1e-5f);
        if (sub == 0) strow[r] = make_float2(rstd, -rstd * mean);
    }
    __syncthreads();   // xb + strow visible; buf0 DMA drained by barrier

    // ---- fragment addressing ----
    const unsigned amask = (unsigned)((l15 & 7) << 4);
    unsigned abase[4];
    #pragma unroll
    for (int m = 0; m < 4; ++m)
        abase[m] = (unsigned)((m * 16 + l15) * 1024 + kb * 16);
    unsigned boff[2];   // B frag read offsets within a Bbuf (swizzled slot)
    #pragma unroll
    for (int n = 0; n < 2; ++n)
        boff[n] = (unsigned)((wave * 32 + n * 16 + l15) * 64 +
                             ((kb ^ ((l15 >> 1) & 3)) * 16));

    f32x4 acc[4][2];

    // ---------------- Phase 2: GEMM1 (LN folded) + GELU -> LDS --------------
    {
        #pragma unroll
        for (int m = 0; m < 4; ++m)
            #pragma unroll
            for (int n = 0; n < 2; ++n)
                acc[m][n] = f32x4{0.f, 0.f, 0.f, 0.f};

        #pragma unroll 2
        for (int ks = 0; ks < 16; ++ks) {
            const int cur = ks & 1;
            asm volatile("s_waitcnt lgkmcnt(0)" ::: "memory");
            if (ks < 15) {               // stage next k-slice into other buffer
                const ushort_t* s0 = W1T + stage_goff + (ks + 1) * 32;
                char* l0 = bwin0 + (cur ^ 1) * BBUF_SZ;
                gload_lds16(s0, l0);
                gload_lds16(s0 + 16 * DIM, l0 + 1024);
                asm volatile("s_waitcnt vmcnt(2)" ::: "memory");  // slice ks landed
            } else {
                asm volatile("s_waitcnt vmcnt(0)" ::: "memory");
            }
            __builtin_amdgcn_sched_barrier(0);
            const char* bb = smem + XB_SZ + cur * BBUF_SZ;
            bf16x8 a[4], b[2];
            #pragma unroll
            for (int n = 0; n < 2; ++n) {
                BU u; u.u = *(const uint4*)(bb + boff[n]);
                b[n] = u.b;
            }
            #pragma unroll
            for (int m = 0; m < 4; ++m) {
                BU u; u.u = *(const uint4*)(smem + ((abase[m] + (unsigned)(ks * 64)) ^ amask));
                a[m] = u.b;
            }
            __builtin_amdgcn_s_setprio(1);
            #pragma unroll
            for (int m = 0; m < 4; ++m)
                #pragma unroll
                for (int n = 0; n < 2; ++n)
                    acc[m][n] = __builtin_amdgcn_mfma_f32_16x16x32_bf16(
                        a[m], b[n], acc[m][n], 0, 0, 0);
            __builtin_amdgcn_s_setprio(0);
        }
        __syncthreads();   // all waves done reading xb

        // stage W2T k-step 0 into buf0 — overlaps GELU epilogue
        gload_lds16(W2T + stage_goff, bwin0);
        gload_lds16(W2T + stage_goff + 16 * DIM, bwin0 + 1024);

        // epilogue: LN scalars + GELU -> overwrite xb with h1 (bf16, swizzled)
        #pragma unroll
        for (int m = 0; m < 4; ++m) {
            const int r0 = m * 16 + kb * 4;
            const float2 sv0 = strow[r0];
            const float2 sv1 = strow[r0 + 1];
            const float2 sv2 = strow[r0 + 2];
            const float2 sv3 = strow[r0 + 3];
            #pragma unroll
            for (int n = 0; n < 2; ++n) {
                const int c = wave * 32 + n * 16 + l15;
                float g0 = gelu_fast(sv0.x * acc[m][n][0] + sv0.y * s1v[n] + bbv[n]);
                float g1 = gelu_fast(sv1.x * acc[m][n][1] + sv1.y * s1v[n] + bbv[n]);
                float g2 = gelu_fast(sv2.x * acc[m][n][2] + sv2.y * s1v[n] + bbv[n]);
                float g3 = gelu_fast(sv3.x * acc[m][n][3] + sv3.y * s1v[n] + bbv[n]);
                unsigned p01 = pk_bf16(g0, g1);
                unsigned p23 = pk_bf16(g2, g3);
                *(ushort_t*)(smem + (unsigned)(((r0    ) * 1024 + c * 2) ^ (((r0    ) & 7) << 4))) = (ushort_t)p01;
                *(ushort_t*)(smem + (unsigned)(((r0 + 1) * 1024 + c * 2) ^ (((r0 + 1) & 7) << 4))) = (ushort_t)(p01 >> 16);
                *(ushort_t*)(smem + (unsigned)(((r0 + 2) * 1024 + c * 2) ^ (((r0 + 2) & 7) << 4))) = (ushort_t)p23;
                *(ushort_t*)(smem + (unsigned)(((r0 + 3) * 1024 + c * 2) ^ (((r0 + 3) & 7) << 4))) = (ushort_t)(p23 >> 16);
            }
        }
    }
    __syncthreads();   // h1 visible; W2T slice0 DMA drained by barrier

    // ---------------- Phase 3: GEMM2 + bias2 + residual -> out (f32) --------
    {
        #pragma unroll
        for (int m = 0; m < 4; ++m)
            #pragma unroll
            for (int n = 0; n < 2; ++n)
                acc[m][n] = f32x4{0.f, 0.f, 0.f, 0.f};

        #pragma unroll 2
        for (int ks = 0; ks < 16; ++ks) {
            const int cur = ks & 1;
            asm volatile("s_waitcnt lgkmcnt(0)" ::: "memory");
            if (ks < 15) {
                const ushort_t* s0 = W2T + stage_goff + (ks + 1) * 32;
                char* l0 = bwin0 + (cur ^ 1) * BBUF_SZ;
                gload_lds16(s0, l0);
                gload_lds16(s0 + 16 * DIM, l0 + 1024);
                asm volatile("s_waitcnt vmcnt(2)" ::: "memory");
            } else {
                asm volatile("s_waitcnt vmcnt(0)" ::: "memory");
            }
            __builtin_amdgcn_sched_barrier(0);
            const char* bb = smem + XB_SZ + cur * BBUF_SZ;
            bf16x8 a[4], b[2];
            #pragma unroll
            for (int n = 0; n < 2; ++n) {
                BU u; u.u = *(const uint4*)(bb + boff[n]);
                b[n] = u.b;
            }
            #pragma unroll
            for (int m = 0; m < 4; ++m) {
                BU u; u.u = *(const uint4*)(smem + ((abase[m] + (unsigned)(ks * 64)) ^ amask));
                a[m] = u.b;
            }
            __builtin_amdgcn_s_setprio(1);
            #pragma unroll
            for (int m = 0; m < 4; ++m)
                #pragma unroll
                for (int n = 0; n < 2; ++n)
                    acc[m][n] = __builtin_amdgcn_mfma_f32_16x16x32_bf16(
                        a[m], b[n], acc[m][n], 0, 0, 0);
            __builtin_amdgcn_s_setprio(0);
        }
        #pragma unroll
        for (int n = 0; n < 2; ++n) {
            const int c = wave * 32 + n * 16 + l15;
            const float bias = b2[c];
            #pragma unroll
            for (int m = 0; m < 4; ++m) {
                #pragma unroll
                for (int i = 0; i < 4; ++i) {
                    const int r = m * 16 + kb * 4 + i;
                    const size_t gi = (rowbase + (size_t)r) * DIM + (size_t)c;
                    out[gi] = x[gi] + (acc[m][n][i] + bias);
                }
            }
        }
    }
}

extern "C" void kernel_launch(void* const* d_in, const int* in_sizes, int n_in,
                              void* d_out, int out_size, void* d_ws, size_t ws_size,
                              hipStream_t stream) {
    const float* x     = (const float*)d_in[0];
    const float* gamma = (const float*)d_in[1];
    const float* beta  = (const float*)d_in[2];
    const float* W1    = (const float*)d_in[3];
    const float* b1    = (const float*)d_in[4];
    const float* W2    = (const float*)d_in[5];
    const float* b2    = (const float*)d_in[6];
    float* out = (float*)d_out;

    char* ws = (char*)d_ws;
    ushort_t* WT  = (ushort_t*)ws;                       // 1 MB: W1gT | W2T
    float*    s1  = (float*)(ws + 1048576);              // 2 KB
    float*    bb1 = (float*)(ws + 1048576 + 2048);       // 2 KB

    prep_weights<<<dim3(DIM / 32, DIM / 32, 2), dim3(32, 8), 0, stream>>>(W1, W2, gamma, WT);
    prep_vecs<<<dim3(DIM / 32), dim3(256), 0, stream>>>(W1, gamma, beta, b1, s1, bb1);
    fused_mlp<<<dim3(N_ROWS / BM), dim3(THREADS), 0, stream>>>(
        x, WT, s1, bb1, WT + DIM * DIM, b2, out);
}

// Round 16
// 157.578 us; speedup vs baseline: 1.2602x; 1.0981x over previous
//
#include <hip/hip_runtime.h>
#include <hip/hip_bf16.h>

#define N_ROWS 65536
#define DIM    512
#define BM     64
#define THREADS 1024
#define XB_SZ   65536
#define BBUF_SZ 32768

typedef unsigned short ushort_t;
typedef __bf16 bf16x8 __attribute__((ext_vector_type(8)));
typedef float  f32x4  __attribute__((ext_vector_type(4)));

union BU { uint4 u; bf16x8 b; };
union BFU { __hip_bfloat162 h2; unsigned u; };

// Packed f32x2 -> bf16x2 (RNE) — compiler emits v_cvt_pk_bf16_f32.
__device__ __forceinline__ unsigned pk_bf16(float lo, float hi) {
    BFU z; z.h2 = __float22bfloat162_rn(float2{lo, hi});
    return z.u;
}

__device__ __forceinline__ unsigned f2bf(float f) {
    unsigned u = __float_as_uint(f);
    return (u + 0x7fffu + ((u >> 16) & 1u)) >> 16;   // RNE f32->bf16 (prep only)
}

// Branchless tanh-form GELU: max abs err ~3e-3 vs exact erf GELU.
__device__ __forceinline__ float gelu_fast(float x) {
    float x2 = x * x;
    float u  = x * (0.7978845608f + 0.0356774081f * x2);
    float a  = fabsf(u);
    float t  = __expf(-2.f * a);
    float th = 1.f - 2.f * t * __builtin_amdgcn_rcpf(1.f + t);
    th = copysignf(th, u);
    return 0.5f * x * (1.f + th);
}

// async global->LDS, 16 bytes per lane; lds dest = wave-uniform base + lane*16
__device__ __forceinline__ void gload_lds16(const ushort_t* g, char* l) {
    __builtin_amdgcn_global_load_lds(
        (const __attribute__((address_space(1))) unsigned int*)g,
        (__attribute__((address_space(3))) unsigned int*)l, 16, 0, 0);
}

// K1a: transpose + gamma-scale (W1 only) + bf16.  W (f32 [k][n]) -> WT (bf16 [n][k])
__global__ void prep_weights(const float* __restrict__ W1,
                             const float* __restrict__ W2,
                             const float* __restrict__ gamma,
                             ushort_t* __restrict__ WT) {
    __shared__ float tile[32][33];
    const int z = blockIdx.z;
    const float* W = z ? W2 : W1;
    ushort_t* dst = WT + (size_t)z * DIM * DIM;
    int n0 = blockIdx.x * 32;
    int k0 = blockIdx.y * 32;
    for (int i = threadIdx.y; i < 32; i += 8) {
        float g = z ? 1.f : gamma[k0 + i];
        tile[i][threadIdx.x] = W[(size_t)(k0 + i) * DIM + n0 + threadIdx.x] * g;
    }
    __syncthreads();
    for (int i = threadIdx.y; i < 32; i += 8)
        dst[(size_t)(n0 + i) * DIM + k0 + threadIdx.x] =
            (ushort_t)f2bf(tile[threadIdx.x][i]);
}

// K1b (parallel): s1[c] = sum_k gamma[k]*W1[k][c];  bb1[c] = b1[c] + sum_k beta[k]*W1[k][c]
__global__ void prep_vecs(const float* __restrict__ W1,
                          const float* __restrict__ gamma,
                          const float* __restrict__ beta,
                          const float* __restrict__ b1,
                          float* __restrict__ s1, float* __restrict__ bb1) {
    __shared__ float red_s[8][32], red_t[8][32];
    const int cl = threadIdx.x & 31;
    const int kp = threadIdx.x >> 5;          // 0..7
    const int c  = blockIdx.x * 32 + cl;
    float s = 0.f, tt = 0.f;
    #pragma unroll 4
    for (int k = kp * 64; k < kp * 64 + 64; ++k) {
        float w = W1[(size_t)k * DIM + c];
        s  += gamma[k] * w;
        tt += beta[k]  * w;
    }
    red_s[kp][cl] = s; red_t[kp][cl] = tt;
    __syncthreads();
    if (kp == 0) {
        float as = 0.f, at = 0.f;
        #pragma unroll
        for (int j = 0; j < 8; ++j) { as += red_s[j][cl]; at += red_t[j][cl]; }
        s1[c]  = as;
        bb1[c] = b1[c] + at;
    }
}

// Fused: stage bf16(x)+stats -> GEMM1(LN-folded,+GELU) -> GEMM2(+bias,+residual)
// R15 frame (173us) + 2-DEEP DMA pipeline (unroll-2, reordered): per step
// vmcnt(2) -> read B -> lgkmcnt(0) (buffer free) -> issue slice ks+2 into it.
__global__ __launch_bounds__(THREADS, 4) void fused_mlp(
    const float* __restrict__ x, const ushort_t* __restrict__ W1T,
    const float* __restrict__ s1, const float* __restrict__ bb1,
    const ushort_t* __restrict__ W2T, const float* __restrict__ b2,
    float* __restrict__ out)
{
    __shared__ __align__(16) char smem[XB_SZ + 2 * BBUF_SZ];  // 128 KB: xb | Bbuf0 | Bbuf1
    __shared__ float2 strow[BM];                              // {rstd, -rstd*mu}
    const int t    = threadIdx.x;
    const int wave = t >> 6;             // 0..15
    const int lane = t & 63;
    const int l15  = lane & 15;
    const int kb   = lane >> 4;          // 0..3
    const size_t rowbase = (size_t)blockIdx.x * BM;

    // ---- staging constants: wave stages 2 windows of 16 n-rows each --------
    const int nl = lane >> 2;            // 0..15 (n within window)
    const int sl = lane & 3;             // 16B slot within 64B row
    const int ssw = sl ^ ((nl >> 1) & 3);               // source-chunk permutation
    const unsigned stage_goff = (unsigned)((wave * 32 + nl) * DIM + ssw * 8); // elements
    char* const bwin0 = smem + XB_SZ + wave * 2048;     // + buf*BBUF_SZ; +1024 -> window 1

    // stage W1T slices 0 AND 1 (both buffers) — drained by the P1 barrier
    gload_lds16(W1T + stage_goff, bwin0);
    gload_lds16(W1T + stage_goff + 16 * DIM, bwin0 + 1024);
    gload_lds16(W1T + stage_goff + 32, bwin0 + BBUF_SZ);
    gload_lds16(W1T + stage_goff + 32 + 16 * DIM, bwin0 + BBUF_SZ + 1024);

    // Per-col folded-LN vectors
    float s1v[2], bbv[2];
    #pragma unroll
    for (int n = 0; n < 2; ++n) {
        int c = wave * 32 + n * 16 + l15;
        s1v[n] = s1[c];
        bbv[n] = bb1[c];
    }

    // ---------------- Phase 1: stream x -> bf16 LDS (swizzled) + row stats ---
    {
        const int r   = t >> 4;          // 0..63
        const int sub = t & 15;          // 16 threads/row, 32 cols each
        const float4* xr = (const float4*)(x + (rowbase + r) * DIM) + sub * 8;
        const unsigned swz  = (unsigned)((r & 7) << 4);
        const unsigned base = (unsigned)(r * 1024 + sub * 64);
        const int rot = (sub >> 1) & 3;  // per-lane chunk rotation
        float s = 0.f, ss = 0.f;
        #pragma unroll
        for (int q = 0; q < 4; ++q) {
            const int p = (q + rot) & 3;
            float4 a = xr[2 * p], b = xr[2 * p + 1];
            s  += a.x + a.y + a.z + a.w + b.x + b.y + b.z + b.w;
            ss += a.x*a.x + a.y*a.y + a.z*a.z + a.w*a.w
                + b.x*b.x + b.y*b.y + b.z*b.z + b.w*b.w;
            uint4 pk;
            pk.x = pk_bf16(a.x, a.y);
            pk.y = pk_bf16(a.z, a.w);
            pk.z = pk_bf16(b.x, b.y);
            pk.w = pk_bf16(b.z, b.w);
            *(uint4*)(smem + ((base + (unsigned)(p * 16)) ^ swz)) = pk;
        }
        #pragma unroll
        for (int m = 1; m < 16; m <<= 1) {
            s  += __shfl_xor(s,  m);
            ss += __shfl_xor(ss, m);
        }
        const float mean = s * (1.f / 512.f);
        const float var  = ss * (1.f / 512.f) - mean * mean;
        const float rstd = rsqrtf(var + 1e-5f);
        if (sub == 0) strow[r] = make_float2(rstd, -rstd * mean);
    }
    __syncthreads();   // xb + strow visible; slices 0,1 drained by barrier

    // ---- fragment addressing ----
    const unsigned amask = (unsigned)((l15 & 7) << 4);
    unsigned abase[4];
    #pragma unroll
    for (int m = 0; m < 4; ++m)
        abase[m] = (unsigned)((m * 16 + l15) * 1024 + kb * 16);
    unsigned boff[2];   // B frag read offsets within a Bbuf (swizzled slot)
    #pragma unroll
    for (int n = 0; n < 2; ++n)
        boff[n] = (unsigned)((wave * 32 + n * 16 + l15) * 64 +
                             ((kb ^ ((l15 >> 1) & 3)) * 16));

    f32x4 acc[4][2];

    // ---------------- Phase 2: GEMM1 (LN folded) + GELU -> LDS --------------
    {
        #pragma unroll
        for (int m = 0; m < 4; ++m)
            #pragma unroll
            for (int n = 0; n < 2; ++n)
                acc[m][n] = f32x4{0.f, 0.f, 0.f, 0.f};

        #pragma unroll 2
        for (int ks = 0; ks < 16; ++ks) {
            const int cur = ks & 1;
            if (ks >= 2) {               // slice ks resident; ks+1 may be in flight
                if (ks == 15) { asm volatile("s_waitcnt vmcnt(0)" ::: "memory"); }
                else          { asm volatile("s_waitcnt vmcnt(2)" ::: "memory"); }
                __builtin_amdgcn_sched_barrier(0);
            }
            const char* bb = smem + XB_SZ + cur * BBUF_SZ;
            bf16x8 a[4], b[2];
            #pragma unroll
            for (int n = 0; n < 2; ++n) {
                BU u; u.u = *(const uint4*)(bb + boff[n]);
                b[n] = u.b;
            }
            // B in regs -> buf[cur] free for slice ks+2
            asm volatile("s_waitcnt lgkmcnt(0)" ::: "memory");
            if (ks < 14) {
                const ushort_t* s0 = W1T + stage_goff + (ks + 2) * 32;
                char* l0 = bwin0 + cur * BBUF_SZ;
                gload_lds16(s0, l0);
                gload_lds16(s0 + 16 * DIM, l0 + 1024);
            }
            #pragma unroll
            for (int m = 0; m < 4; ++m) {
                BU u; u.u = *(const uint4*)(smem + ((abase[m] + (unsigned)(ks * 64)) ^ amask));
                a[m] = u.b;
            }
            __builtin_amdgcn_s_setprio(1);
            #pragma unroll
            for (int m = 0; m < 4; ++m)
                #pragma unroll
                for (int n = 0; n < 2; ++n)
                    acc[m][n] = __builtin_amdgcn_mfma_f32_16x16x32_bf16(
                        a[m], b[n], acc[m][n], 0, 0, 0);
            __builtin_amdgcn_s_setprio(0);
        }
        __syncthreads();   // all waves done reading xb

        // stage W2T slices 0,1 — overlap GELU epilogue; drained by next barrier
        gload_lds16(W2T + stage_goff, bwin0);
        gload_lds16(W2T + stage_goff + 16 * DIM, bwin0 + 1024);
        gload_lds16(W2T + stage_goff + 32, bwin0 + BBUF_SZ);
        gload_lds16(W2T + stage_goff + 32 + 16 * DIM, bwin0 + BBUF_SZ + 1024);

        // epilogue: LN scalars + GELU -> overwrite xb with h1 (bf16, swizzled)
        #pragma unroll
        for (int m = 0; m < 4; ++m) {
            const int r0 = m * 16 + kb * 4;
            const float2 sv0 = strow[r0];
            const float2 sv1 = strow[r0 + 1];
            const float2 sv2 = strow[r0 + 2];
            const float2 sv3 = strow[r0 + 3];
            #pragma unroll
            for (int n = 0; n < 2; ++n) {
                const int c = wave * 32 + n * 16 + l15;
                float g0 = gelu_fast(sv0.x * acc[m][n][0] + sv0.y * s1v[n] + bbv[n]);
                float g1 = gelu_fast(sv1.x * acc[m][n][1] + sv1.y * s1v[n] + bbv[n]);
                float g2 = gelu_fast(sv2.x * acc[m][n][2] + sv2.y * s1v[n] + bbv[n]);
                float g3 = gelu_fast(sv3.x * acc[m][n][3] + sv3.y * s1v[n] + bbv[n]);
                unsigned p01 = pk_bf16(g0, g1);
                unsigned p23 = pk_bf16(g2, g3);
                *(ushort_t*)(smem + (unsigned)(((r0    ) * 1024 + c * 2) ^ (((r0    ) & 7) << 4))) = (ushort_t)p01;
                *(ushort_t*)(smem + (unsigned)(((r0 + 1) * 1024 + c * 2) ^ (((r0 + 1) & 7) << 4))) = (ushort_t)(p01 >> 16);
                *(ushort_t*)(smem + (unsigned)(((r0 + 2) * 1024 + c * 2) ^ (((r0 + 2) & 7) << 4))) = (ushort_t)p23;
                *(ushort_t*)(smem + (unsigned)(((r0 + 3) * 1024 + c * 2) ^ (((r0 + 3) & 7) << 4))) = (ushort_t)(p23 >> 16);
            }
        }
    }
    __syncthreads();   // h1 visible; W2T slices 0,1 drained by barrier

    // ---------------- Phase 3: GEMM2 + bias2 + residual -> out (f32) --------
    {
        #pragma unroll
        for (int m = 0; m < 4; ++m)
            #pragma unroll
            for (int n = 0; n < 2; ++n)
                acc[m][n] = f32x4{0.f, 0.f, 0.f, 0.f};

        #pragma unroll 2
        for (int ks = 0; ks < 16; ++ks) {
            const int cur = ks & 1;
            if (ks >= 2) {
                if (ks == 15) { asm volatile("s_waitcnt vmcnt(0)" ::: "memory"); }
                else          { asm volatile("s_waitcnt vmcnt(2)" ::: "memory"); }
                __builtin_amdgcn_sched_barrier(0);
            }
            const char* bb = smem + XB_SZ + cur * BBUF_SZ;
            bf16x8 a[4], b[2];
            #pragma unroll
            for (int n = 0; n < 2; ++n) {
                BU u; u.u = *(const uint4*)(bb + boff[n]);
                b[n] = u.b;
            }
            asm volatile("s_waitcnt lgkmcnt(0)" ::: "memory");
            if (ks < 14) {
                const ushort_t* s0 = W2T + stage_goff + (ks + 2) * 32;
                char* l0 = bwin0 + cur * BBUF_SZ;
                gload_lds16(s0, l0);
                gload_lds16(s0 + 16 * DIM, l0 + 1024);
            }
            #pragma unroll
            for (int m = 0; m < 4; ++m) {
                BU u; u.u = *(const uint4*)(smem + ((abase[m] + (unsigned)(ks * 64)) ^ amask));
                a[m] = u.b;
            }
            __builtin_amdgcn_s_setprio(1);
            #pragma unroll
            for (int m = 0; m < 4; ++m)
                #pragma unroll
                for (int n = 0; n < 2; ++n)
                    acc[m][n] = __builtin_amdgcn_mfma_f32_16x16x32_bf16(
                        a[m], b[n], acc[m][n], 0, 0, 0);
            __builtin_amdgcn_s_setprio(0);
        }
        #pragma unroll
        for (int n = 0; n < 2; ++n) {
            const int c = wave * 32 + n * 16 + l15;
            const float bias = b2[c];
            #pragma unroll
            for (int m = 0; m < 4; ++m) {
                #pragma unroll
                for (int i = 0; i < 4; ++i) {
                    const int r = m * 16 + kb * 4 + i;
                    const size_t gi = (rowbase + (size_t)r) * DIM + (size_t)c;
                    out[gi] = x[gi] + (acc[m][n][i] + bias);
                }
            }
        }
    }
}

extern "C" void kernel_launch(void* const* d_in, const int* in_sizes, int n_in,
                              void* d_out, int out_size, void* d_ws, size_t ws_size,
                              hipStream_t stream) {
    const float* x     = (const float*)d_in[0];
    const float* gamma = (const float*)d_in[1];
    const float* beta  = (const float*)d_in[2];
    const float* W1    = (const float*)d_in[3];
    const float* b1    = (const float*)d_in[4];
    const float* W2    = (const float*)d_in[5];
    const float* b2    = (const float*)d_in[6];
    float* out = (float*)d_out;

    char* ws = (char*)d_ws;
    ushort_t* WT  = (ushort_t*)ws;                       // 1 MB: W1gT | W2T
    float*    s1  = (float*)(ws + 1048576);              // 2 KB
    float*    bb1 = (float*)(ws + 1048576 + 2048);       // 2 KB

    prep_weights<<<dim3(DIM / 32, DIM / 32, 2), dim3(32, 8), 0, stream>>>(W1, W2, gamma, WT);
    prep_vecs<<<dim3(DIM / 32), dim3(256), 0, stream>>>(W1, gamma, beta, b1, s1, bb1);
    fused_mlp<<<dim3(N_ROWS / BM), dim3(THREADS), 0, stream>>>(
        x, WT, s1, bb1, WT + DIM * DIM, b2, out);
}

// Round 17
// 151.015 us; speedup vs baseline: 1.3150x; 1.0435x over previous
//
#include <hip/hip_runtime.h>
#include <hip/hip_bf16.h>

#define N_ROWS 65536
#define DIM    512
#define BM     64
#define THREADS 1024
#define XB_SZ   65536
#define BBUF_SZ 32768

typedef unsigned short ushort_t;
typedef __bf16 bf16x8 __attribute__((ext_vector_type(8)));
typedef float  f32x4  __attribute__((ext_vector_type(4)));

union BU { uint4 u; bf16x8 b; };
union BFU { __hip_bfloat162 h2; unsigned u; };

// Packed f32x2 -> bf16x2 (RNE) — compiler emits v_cvt_pk_bf16_f32.
__device__ __forceinline__ unsigned pk_bf16(float lo, float hi) {
    BFU z; z.h2 = __float22bfloat162_rn(float2{lo, hi});
    return z.u;
}

__device__ __forceinline__ unsigned f2bf(float f) {
    unsigned u = __float_as_uint(f);
    return (u + 0x7fffu + ((u >> 16) & 1u)) >> 16;   // RNE f32->bf16 (prep only)
}

// Sigmoid-form GELU: x*sigmoid(1.702x). ~5 VALU ops (vs ~11 tanh-form).
// Max approx err ~0.02 on h1; attenuated through W2 -> out err ~0.02-0.03.
// Limits: x->-inf: exp->inf, rcp->0, g=0. x->+inf: exp->0, g=x.
__device__ __forceinline__ float gelu_fast(float x) {
    return x * __builtin_amdgcn_rcpf(1.f + __expf(-1.702f * x));
}

// async global->LDS, 16 bytes per lane; lds dest = wave-uniform base + lane*16
__device__ __forceinline__ void gload_lds16(const ushort_t* g, char* l) {
    __builtin_amdgcn_global_load_lds(
        (const __attribute__((address_space(1))) unsigned int*)g,
        (__attribute__((address_space(3))) unsigned int*)l, 16, 0, 0);
}

// Merged prep: z<2 -> transpose + gamma-scale W1/W2 into bf16 [n][k];
// z==2 (y==0 blocks only) -> s1/bb1 column sums.
__global__ void prep_all(const float* __restrict__ W1,
                         const float* __restrict__ W2,
                         const float* __restrict__ gamma,
                         const float* __restrict__ beta,
                         const float* __restrict__ b1,
                         ushort_t* __restrict__ WT,
                         float* __restrict__ s1, float* __restrict__ bb1) {
    __shared__ float tile[32][33];
    const int z = blockIdx.z;
    if (z < 2) {
        const float* W = z ? W2 : W1;
        ushort_t* dst = WT + (size_t)z * DIM * DIM;
        int n0 = blockIdx.x * 32;
        int k0 = blockIdx.y * 32;
        for (int i = threadIdx.y; i < 32; i += 8) {
            float g = z ? 1.f : gamma[k0 + i];
            tile[i][threadIdx.x] = W[(size_t)(k0 + i) * DIM + n0 + threadIdx.x] * g;
        }
        __syncthreads();
        for (int i = threadIdx.y; i < 32; i += 8)
            dst[(size_t)(n0 + i) * DIM + k0 + threadIdx.x] =
                (ushort_t)f2bf(tile[threadIdx.x][i]);
    } else {
        if (blockIdx.y != 0) return;
        float (*red_s)[32] = (float(*)[32])&tile[0][0];   // 8x32
        float (*red_t)[32] = (float(*)[32])&tile[8][0];   // 8x32 (fits in tile)
        const int cl = threadIdx.x;          // 0..31
        const int kp = threadIdx.y;          // 0..7
        const int c  = blockIdx.x * 32 + cl;
        float s = 0.f, tt = 0.f;
        #pragma unroll 4
        for (int k = kp * 64; k < kp * 64 + 64; ++k) {
            float w = W1[(size_t)k * DIM + c];
            s  += gamma[k] * w;
            tt += beta[k]  * w;
        }
        red_s[kp][cl] = s; red_t[kp][cl] = tt;
        __syncthreads();
        if (kp == 0) {
            float as = 0.f, at = 0.f;
            #pragma unroll
            for (int j = 0; j < 8; ++j) { as += red_s[j][cl]; at += red_t[j][cl]; }
            s1[c]  = as;
            bb1[c] = b1[c] + at;
        }
    }
}

// Fused: stage bf16(x)+stats -> GEMM1(LN-folded,+GELU) -> GEMM2(+bias,+residual)
// R16 frame (157.6us): barrier-free wave-private k-loops, 2-deep DMA pipeline.
// R17: sigmoid-GELU (5-op) + merged prep kernel.
__global__ __launch_bounds__(THREADS, 4) void fused_mlp(
    const float* __restrict__ x, const ushort_t* __restrict__ W1T,
    const float* __restrict__ s1, const float* __restrict__ bb1,
    const ushort_t* __restrict__ W2T, const float* __restrict__ b2,
    float* __restrict__ out)
{
    __shared__ __align__(16) char smem[XB_SZ + 2 * BBUF_SZ];  // 128 KB: xb | Bbuf0 | Bbuf1
    __shared__ float2 strow[BM];                              // {rstd, -rstd*mu}
    const int t    = threadIdx.x;
    const int wave = t >> 6;             // 0..15
    const int lane = t & 63;
    const int l15  = lane & 15;
    const int kb   = lane >> 4;          // 0..3
    const size_t rowbase = (size_t)blockIdx.x * BM;

    // ---- staging constants: wave stages 2 windows of 16 n-rows each --------
    const int nl = lane >> 2;            // 0..15 (n within window)
    const int sl = lane & 3;             // 16B slot within 64B row
    const int ssw = sl ^ ((nl >> 1) & 3);               // source-chunk permutation
    const unsigned stage_goff = (unsigned)((wave * 32 + nl) * DIM + ssw * 8); // elements
    char* const bwin0 = smem + XB_SZ + wave * 2048;     // + buf*BBUF_SZ; +1024 -> window 1

    // stage W1T slices 0 AND 1 (both buffers) — drained by the P1 barrier
    gload_lds16(W1T + stage_goff, bwin0);
    gload_lds16(W1T + stage_goff + 16 * DIM, bwin0 + 1024);
    gload_lds16(W1T + stage_goff + 32, bwin0 + BBUF_SZ);
    gload_lds16(W1T + stage_goff + 32 + 16 * DIM, bwin0 + BBUF_SZ + 1024);

    // Per-col folded-LN vectors
    float s1v[2], bbv[2];
    #pragma unroll
    for (int n = 0; n < 2; ++n) {
        int c = wave * 32 + n * 16 + l15;
        s1v[n] = s1[c];
        bbv[n] = bb1[c];
    }

    // ---------------- Phase 1: stream x -> bf16 LDS (swizzled) + row stats ---
    {
        const int r   = t >> 4;          // 0..63
        const int sub = t & 15;          // 16 threads/row, 32 cols each
        const float4* xr = (const float4*)(x + (rowbase + r) * DIM) + sub * 8;
        const unsigned swz  = (unsigned)((r & 7) << 4);
        const unsigned base = (unsigned)(r * 1024 + sub * 64);
        const int rot = (sub >> 1) & 3;  // per-lane chunk rotation
        float s = 0.f, ss = 0.f;
        #pragma unroll
        for (int q = 0; q < 4; ++q) {
            const int p = (q + rot) & 3;
            float4 a = xr[2 * p], b = xr[2 * p + 1];
            s  += a.x + a.y + a.z + a.w + b.x + b.y + b.z + b.w;
            ss += a.x*a.x + a.y*a.y + a.z*a.z + a.w*a.w
                + b.x*b.x + b.y*b.y + b.z*b.z + b.w*b.w;
            uint4 pk;
            pk.x = pk_bf16(a.x, a.y);
            pk.y = pk_bf16(a.z, a.w);
            pk.z = pk_bf16(b.x, b.y);
            pk.w = pk_bf16(b.z, b.w);
            *(uint4*)(smem + ((base + (unsigned)(p * 16)) ^ swz)) = pk;
        }
        #pragma unroll
        for (int m = 1; m < 16; m <<= 1) {
            s  += __shfl_xor(s,  m);
            ss += __shfl_xor(ss, m);
        }
        const float mean = s * (1.f / 512.f);
        const float var  = ss * (1.f / 512.f) - mean * mean;
        const float rstd = rsqrtf(var + 1e-5f);
        if (sub == 0) strow[r] = make_float2(rstd, -rstd * mean);
    }
    __syncthreads();   // xb + strow visible; slices 0,1 drained by barrier

    // ---- fragment addressing ----
    const unsigned amask = (unsigned)((l15 & 7) << 4);
    unsigned abase[4];
    #pragma unroll
    for (int m = 0; m < 4; ++m)
        abase[m] = (unsigned)((m * 16 + l15) * 1024 + kb * 16);
    unsigned boff[2];   // B frag read offsets within a Bbuf (swizzled slot)
    #pragma unroll
    for (int n = 0; n < 2; ++n)
        boff[n] = (unsigned)((wave * 32 + n * 16 + l15) * 64 +
                             ((kb ^ ((l15 >> 1) & 3)) * 16));

    f32x4 acc[4][2];

    // ---------------- Phase 2: GEMM1 (LN folded) + GELU -> LDS --------------
    {
        #pragma unroll
        for (int m = 0; m < 4; ++m)
            #pragma unroll
            for (int n = 0; n < 2; ++n)
                acc[m][n] = f32x4{0.f, 0.f, 0.f, 0.f};

        #pragma unroll 2
        for (int ks = 0; ks < 16; ++ks) {
            const int cur = ks & 1;
            if (ks >= 2) {               // slice ks resident; ks+1 may be in flight
                if (ks == 15) { asm volatile("s_waitcnt vmcnt(0)" ::: "memory"); }
                else          { asm volatile("s_waitcnt vmcnt(2)" ::: "memory"); }
                __builtin_amdgcn_sched_barrier(0);
            }
            const char* bb = smem + XB_SZ + cur * BBUF_SZ;
            bf16x8 a[4], b[2];
            #pragma unroll
            for (int n = 0; n < 2; ++n) {
                BU u; u.u = *(const uint4*)(bb + boff[n]);
                b[n] = u.b;
            }
            // B in regs -> buf[cur] free for slice ks+2
            asm volatile("s_waitcnt lgkmcnt(0)" ::: "memory");
            if (ks < 14) {
                const ushort_t* s0 = W1T + stage_goff + (ks + 2) * 32;
                char* l0 = bwin0 + cur * BBUF_SZ;
                gload_lds16(s0, l0);
                gload_lds16(s0 + 16 * DIM, l0 + 1024);
            }
            #pragma unroll
            for (int m = 0; m < 4; ++m) {
                BU u; u.u = *(const uint4*)(smem + ((abase[m] + (unsigned)(ks * 64)) ^ amask));
                a[m] = u.b;
            }
            __builtin_amdgcn_s_setprio(1);
            #pragma unroll
            for (int m = 0; m < 4; ++m)
                #pragma unroll
                for (int n = 0; n < 2; ++n)
                    acc[m][n] = __builtin_amdgcn_mfma_f32_16x16x32_bf16(
                        a[m], b[n], acc[m][n], 0, 0, 0);
            __builtin_amdgcn_s_setprio(0);
        }
        __syncthreads();   // all waves done reading xb

        // stage W2T slices 0,1 — overlap GELU epilogue; drained by next barrier
        gload_lds16(W2T + stage_goff, bwin0);
        gload_lds16(W2T + stage_goff + 16 * DIM, bwin0 + 1024);
        gload_lds16(W2T + stage_goff + 32, bwin0 + BBUF_SZ);
        gload_lds16(W2T + stage_goff + 32 + 16 * DIM, bwin0 + BBUF_SZ + 1024);

        // epilogue: LN scalars + GELU -> overwrite xb with h1 (bf16, swizzled)
        #pragma unroll
        for (int m = 0; m < 4; ++m) {
            const int r0 = m * 16 + kb * 4;
            const float2 sv0 = strow[r0];
            const float2 sv1 = strow[r0 + 1];
            const float2 sv2 = strow[r0 + 2];
            const float2 sv3 = strow[r0 + 3];
            #pragma unroll
            for (int n = 0; n < 2; ++n) {
                const int c = wave * 32 + n * 16 + l15;
                float g0 = gelu_fast(sv0.x * acc[m][n][0] + sv0.y * s1v[n] + bbv[n]);
                float g1 = gelu_fast(sv1.x * acc[m][n][1] + sv1.y * s1v[n] + bbv[n]);
                float g2 = gelu_fast(sv2.x * acc[m][n][2] + sv2.y * s1v[n] + bbv[n]);
                float g3 = gelu_fast(sv3.x * acc[m][n][3] + sv3.y * s1v[n] + bbv[n]);
                unsigned p01 = pk_bf16(g0, g1);
                unsigned p23 = pk_bf16(g2, g3);
                *(ushort_t*)(smem + (unsigned)(((r0    ) * 1024 + c * 2) ^ (((r0    ) & 7) << 4))) = (ushort_t)p01;
                *(ushort_t*)(smem + (unsigned)(((r0 + 1) * 1024 + c * 2) ^ (((r0 + 1) & 7) << 4))) = (ushort_t)(p01 >> 16);
                *(ushort_t*)(smem + (unsigned)(((r0 + 2) * 1024 + c * 2) ^ (((r0 + 2) & 7) << 4))) = (ushort_t)p23;
                *(ushort_t*)(smem + (unsigned)(((r0 + 3) * 1024 + c * 2) ^ (((r0 + 3) & 7) << 4))) = (ushort_t)(p23 >> 16);
            }
        }
    }
    __syncthreads();   // h1 visible; W2T slices 0,1 drained by barrier

    // ---------------- Phase 3: GEMM2 + bias2 + residual -> out (f32) --------
    {
        #pragma unroll
        for (int m = 0; m < 4; ++m)
            #pragma unroll
            for (int n = 0; n < 2; ++n)
                acc[m][n] = f32x4{0.f, 0.f, 0.f, 0.f};

        #pragma unroll 2
        for (int ks = 0; ks < 16; ++ks) {
            const int cur = ks & 1;
            if (ks >= 2) {
                if (ks == 15) { asm volatile("s_waitcnt vmcnt(0)" ::: "memory"); }
                else          { asm volatile("s_waitcnt vmcnt(2)" ::: "memory"); }
                __builtin_amdgcn_sched_barrier(0);
            }
            const char* bb = smem + XB_SZ + cur * BBUF_SZ;
            bf16x8 a[4], b[2];
            #pragma unroll
            for (int n = 0; n < 2; ++n) {
                BU u; u.u = *(const uint4*)(bb + boff[n]);
                b[n] = u.b;
            }
            asm volatile("s_waitcnt lgkmcnt(0)" ::: "memory");
            if (ks < 14) {
                const ushort_t* s0 = W2T + stage_goff + (ks + 2) * 32;
                char* l0 = bwin0 + cur * BBUF_SZ;
                gload_lds16(s0, l0);
                gload_lds16(s0 + 16 * DIM, l0 + 1024);
            }
            #pragma unroll
            for (int m = 0; m < 4; ++m) {
                BU u; u.u = *(const uint4*)(smem + ((abase[m] + (unsigned)(ks * 64)) ^ amask));
                a[m] = u.b;
            }
            __builtin_amdgcn_s_setprio(1);
            #pragma unroll
            for (int m = 0; m < 4; ++m)
                #pragma unroll
                for (int n = 0; n < 2; ++n)
                    acc[m][n] = __builtin_amdgcn_mfma_f32_16x16x32_bf16(
                        a[m], b[n], acc[m][n], 0, 0, 0);
            __builtin_amdgcn_s_setprio(0);
        }
        #pragma unroll
        for (int n = 0; n < 2; ++n) {
            const int c = wave * 32 + n * 16 + l15;
            const float bias = b2[c];
            #pragma unroll
            for (int m = 0; m < 4; ++m) {
                #pragma unroll
                for (int i = 0; i < 4; ++i) {
                    const int r = m * 16 + kb * 4 + i;
                    const size_t gi = (rowbase + (size_t)r) * DIM + (size_t)c;
                    out[gi] = x[gi] + (acc[m][n][i] + bias);
                }
            }
        }
    }
}

extern "C" void kernel_launch(void* const* d_in, const int* in_sizes, int n_in,
                              void* d_out, int out_size, void* d_ws, size_t ws_size,
                              hipStream_t stream) {
    const float* x     = (const float*)d_in[0];
    const float* gamma = (const float*)d_in[1];
    const float* beta  = (const float*)d_in[2];
    const float* W1    = (const float*)d_in[3];
    const float* b1    = (const float*)d_in[4];
    const float* W2    = (const float*)d_in[5];
    const float* b2    = (const float*)d_in[6];
    float* out = (float*)d_out;

    char* ws = (char*)d_ws;
    ushort_t* WT  = (ushort_t*)ws;                       // 1 MB: W1gT | W2T
    float*    s1  = (float*)(ws + 1048576);              // 2 KB
    float*    bb1 = (float*)(ws + 1048576 + 2048);       // 2 KB

    prep_all<<<dim3(DIM / 32, DIM / 32, 3), dim3(32, 8), 0, stream>>>(
        W1, W2, gamma, beta, b1, WT, s1, bb1);
    fused_mlp<<<dim3(N_ROWS / BM), dim3(THREADS), 0, stream>>>(
        x, WT, s1, bb1, WT + DIM * DIM, b2, out);
}